// Round 15
// baseline (193.496 us; speedup 1.0000x reference)
//
#include <hip/hip_runtime.h>
#include <hip/hip_bf16.h>

// KAN layer = GEMM: out[b,o] = sum_{i,k} T_k(tanh(x[b,i])) * W[o,i,k] + bias[o]
// v12 = v11 with the split-K merge moved INSIDE the block.
//   512-thread blocks: waves 0-3 run K-half 0, waves 4-7 run K-half 1 --
//   each group is exactly v11's proven 4-wave pipeline on its own 32 KB LDS
//   pair. After the last barrier the staging LDS is dead; kh1 dumps its
//   accumulators there, kh0 adds + bias + stores. Deletes the reduce kernel
//   and the P1 HBM round-trip (~11 us), and doubles TLP to 4 waves/SIMD
//   (16 waves/CU), which should close part of v11's 25% gap to the LDS floor.
#define MD 4096
#define ND 1024
#define KD 8192
#define IN_F 1024

typedef __bf16 bf16x8 __attribute__((ext_vector_type(8)));
typedef float f32x4 __attribute__((ext_vector_type(4)));

// ---------------- Pass 1 (merged): basis + W convert ----------------
#define N_BASIS (MD * IN_F)
#define N_CONV ((ND * KD) / 8)

__global__ __launch_bounds__(256) void prep_kernel(
    const float* __restrict__ x, const float* __restrict__ w,
    __bf16* __restrict__ A, __bf16* __restrict__ B) {
  int i = blockIdx.x * blockDim.x + threadIdx.x;
  if (i < N_BASIS) {
    float t = tanhf(x[i]);
    float two_t = 2.0f * t;
    float T0 = 1.0f;
    float T1 = t;
    float T2 = two_t * T1 - T0;
    float T3 = two_t * T2 - T1;
    float T4 = two_t * T3 - T2;
    float T5 = two_t * T4 - T3;
    float T6 = two_t * T5 - T4;
    float T7 = two_t * T6 - T5;
    bf16x8 v;
    v[0] = (__bf16)T0; v[1] = (__bf16)T1; v[2] = (__bf16)T2; v[3] = (__bf16)T3;
    v[4] = (__bf16)T4; v[5] = (__bf16)T5; v[6] = (__bf16)T6; v[7] = (__bf16)T7;
    *(bf16x8*)(A + (size_t)i * 8) = v;
  } else if (i < N_BASIS + N_CONV) {
    int j = i - N_BASIS;
    const float4* p = (const float4*)(w + (size_t)j * 8);
    float4 a = p[0], b = p[1];
    bf16x8 v;
    v[0] = (__bf16)a.x; v[1] = (__bf16)a.y; v[2] = (__bf16)a.z; v[3] = (__bf16)a.w;
    v[4] = (__bf16)b.x; v[5] = (__bf16)b.y; v[6] = (__bf16)b.z; v[7] = (__bf16)b.w;
    *(bf16x8*)(B + (size_t)j * 8) = v;
  }
}

// ---------------- Pass 2: GEMM_BT + in-block split-K + bias ----------------
#define BM 128
#define BN 128
#define BK 64
#define KHALF 4096
#define TSZ (BM * BK)      // 8192 bf16 = 16 KB per tile

__global__ __launch_bounds__(512, 4) void gemm_bias(
    const __bf16* __restrict__ A, const __bf16* __restrict__ B,
    const float* __restrict__ bias, float* __restrict__ C) {
  // [kh][tile]; 64 KB total. Reused as the 64 KB fp32 merge buffer at the end.
  __shared__ __align__(16) __bf16 As[2][TSZ];
  __shared__ __align__(16) __bf16 Bs[2][TSZ];

  const int tid = threadIdx.x;
  const int wave = tid >> 6;    // 0..7
  const int kh = wave >> 2;     // 0..1 : K-half owner
  const int w4 = wave & 3;      // 0..3 : wave within the kh-group
  const int lane = tid & 63;

  // A-resident XCD swizzle (R10-validated): 256 blocks, b = xcd + 8*(nt+8*mloc)
  const int b = blockIdx.x;
  const int xcd = b & 7;
  const int j = b >> 3;         // 0..31
  const int nt = j & 7;         // 0..7
  const int mloc = j >> 3;      // 0..3
  const int n0 = nt * BN;
  const int m0 = (xcd * 4 + mloc) * BM;
  const size_t k0 = (size_t)kh * KHALF;

  const int wm = w4 >> 1;       // 0..1
  const int wn = w4 & 1;        // 0..1

  // ---- staging (v11-proven): one glds (16B/lane) covers 8 rows of 128B.
  // XOR swizzle on the GLOBAL side: slot (r,pg) holds logical group pg^ar.
  const int ar = lane >> 3;
  const int swz_col = ((lane & 7) ^ ar) * 8;
  const __bf16* gA = A + (size_t)(m0 + w4 * 32 + ar) * KD + k0 + swz_col;
  const __bf16* gB = B + (size_t)(n0 + w4 * 32 + ar) * KD + k0 + swz_col;
  const int loff = w4 * 32 * BK;

  f32x4 acc[4][4];
#pragma unroll
  for (int i = 0; i < 4; i++)
#pragma unroll
    for (int jj = 0; jj < 4; jj++) acc[i][jj] = (f32x4){0.f, 0.f, 0.f, 0.f};

  // ---- fragment coords (16x16x32: row=lane&15, k=(lane>>4)*8+jj)
  const int fr = lane & 15;
  const int fr7 = fr & 7;
  const int qk = lane >> 4;    // 0..3

  // ---- main loop (v8/v11-proven 2-barrier pattern; barriers now span both
  // symmetric kh-groups)
  for (int kt = 0; kt < KHALF; kt += BK) {
#pragma unroll
    for (int jj = 0; jj < 4; jj++) {
      __builtin_amdgcn_global_load_lds(
          (const __attribute__((address_space(1))) void*)(gA + kt + (size_t)jj * 8 * KD),
          (__attribute__((address_space(3))) void*)(&As[kh][loff + jj * 8 * BK]), 16, 0, 0);
      __builtin_amdgcn_global_load_lds(
          (const __attribute__((address_space(1))) void*)(gB + kt + (size_t)jj * 8 * KD),
          (__attribute__((address_space(3))) void*)(&Bs[kh][loff + jj * 8 * BK]), 16, 0, 0);
    }
    __syncthreads();

#pragma unroll
    for (int s = 0; s < 2; s++) {
      const int pa = ((s * 4 + qk) ^ fr7) * 8;
      bf16x8 af[4], bfr[4];
#pragma unroll
      for (int mi = 0; mi < 4; mi++)
        af[mi] = *(const bf16x8*)&As[kh][(wm * 64 + mi * 16 + fr) * BK + pa];
#pragma unroll
      for (int ni = 0; ni < 4; ni++)
        bfr[ni] = *(const bf16x8*)&Bs[kh][(wn * 64 + ni * 16 + fr) * BK + pa];
#pragma unroll
      for (int mi = 0; mi < 4; mi++)
#pragma unroll
        for (int ni = 0; ni < 4; ni++)
          acc[mi][ni] = __builtin_amdgcn_mfma_f32_16x16x32_bf16(
              af[mi], bfr[ni], acc[mi][ni], 0, 0, 0);
    }
    __syncthreads();
  }

  // ---- in-block split-K merge. Staging LDS is dead after the last barrier;
  // reuse all 64 KB as an fp32 buffer. Element correspondence is by identical
  // (w4, lane, mi, ni) coords, so indexing is symmetric and dense b128.
  float* M = (float*)&As[0][0];  // 16384 floats = 64 KB
  if (kh == 1) {
#pragma unroll
    for (int mi = 0; mi < 4; mi++)
#pragma unroll
      for (int ni = 0; ni < 4; ni++)
        *(f32x4*)&M[((w4 * 16 + mi * 4 + ni) * 64 + lane) * 4] = acc[mi][ni];
  }
  __syncthreads();
  if (kh == 0) {
    // epilogue (v9/v11-proven): C/D col=lane&15, row=(lane>>4)*4+r ; add bias
    const int col0 = n0 + wn * 64;
    const int row0 = m0 + wm * 64 + qk * 4;
#pragma unroll
    for (int ni = 0; ni < 4; ni++) {
      int col = col0 + ni * 16 + fr;
      float bv = bias[col];
#pragma unroll
      for (int mi = 0; mi < 4; mi++) {
        f32x4 other = *(const f32x4*)&M[((w4 * 16 + mi * 4 + ni) * 64 + lane) * 4];
        int row = row0 + mi * 16;
#pragma unroll
        for (int r = 0; r < 4; r++)
          C[(size_t)(row + r) * ND + col] = acc[mi][ni][r] + other[r] + bv;
      }
    }
  }
}

extern "C" void kernel_launch(void* const* d_in, const int* in_sizes, int n_in,
                              void* d_out, int out_size, void* d_ws, size_t ws_size,
                              hipStream_t stream) {
  const float* x = (const float*)d_in[0];     // [4096,1024]
  const float* w = (const float*)d_in[1];     // [1024,1024,8]
  const float* bias = (const float*)d_in[2];  // [1024]
  float* out = (float*)d_out;                 // [4096,1024]

  __bf16* Abf = (__bf16*)d_ws;                                 // 64 MB
  __bf16* Bbf = (__bf16*)((char*)d_ws + (size_t)MD * KD * 2);  // 16 MB

  {  // merged basis + convert
    int n = N_BASIS + N_CONV;
    prep_kernel<<<(n + 255) / 256, 256, 0, stream>>>(x, w, Abf, Bbf);
  }
  {  // GEMM + in-block split-K + bias: 256 blocks x 512 threads, 2 blocks/CU
    gemm_bias<<<256, 512, 0, stream>>>(Abf, Bbf, bias, out);
  }
}